// Round 4
// baseline (430.457 us; speedup 1.0000x reference)
//
#include <hip/hip_runtime.h>
#include <stdint.h>

// BraidCrossing: scale = mean(softmax(.), axis=-1) == 1/6 exactly => W1/b1/W2/b2/gelu dead.
// out_t = LN(LN(x_t + P_{t-1}/6) + P_{t+1}/6), P = x @ Wp^T + bp, one-sided at t=0, T-1.
// R7: GEMM = proven R6 kernel, split into two M-half dispatches (~65us each) so the
// cast/ln dispatches become visible in rocprof top-5. LN-v3 = wave-per-row (max TLP,
// 4096 blocks) with ALL loads (x, P_{t-1}, P_{t+1}) issued before any compute — one
// latency exposure per row, not two; gamma/beta reloaded from L1 per stage to keep
// VGPR ~100 (5 waves/SIMD).

#define B_DIM 8
#define T_DIM 2048
#define D_DIM 2048
#define M_DIM (B_DIM * T_DIM)   // 16384
#define N_DIM D_DIM             // 2048
#define K_DIM D_DIM             // 2048

typedef __attribute__((ext_vector_type(8))) short short8;   // 8 bf16 in 4 VGPRs
typedef __attribute__((ext_vector_type(4))) float f32x4;

__device__ inline unsigned short f2bf(float f) {
    unsigned u = __float_as_uint(f);
    u += 0x7fffu + ((u >> 16) & 1u);   // RTNE
    return (unsigned short)(u >> 16);
}
__device__ inline float bf2f(unsigned u16) {
    return __uint_as_float(u16 << 16);
}
__device__ inline void unpack8(uint4 u, float* f) {
    f[0] = bf2f(u.x & 0xffffu); f[1] = bf2f(u.x >> 16);
    f[2] = bf2f(u.y & 0xffffu); f[3] = bf2f(u.y >> 16);
    f[4] = bf2f(u.z & 0xffffu); f[5] = bf2f(u.z >> 16);
    f[6] = bf2f(u.w & 0xffffu); f[7] = bf2f(u.w >> 16);
}
__device__ inline void async_ld16(const void* g, void* l) {
    __builtin_amdgcn_global_load_lds(
        (__attribute__((address_space(1))) void*)(g),
        (__attribute__((address_space(3))) void*)(l),
        16, 0, 0);
}

// ---------------- cast f32 -> bf16 (x and Wp in one launch, grid-stride) ----------------
__global__ void cast_f32_bf16(const float* __restrict__ x, unsigned short* __restrict__ Xb,
                              const float* __restrict__ Wp, unsigned short* __restrict__ Wb,
                              int nx4, int ntot4) {
    for (int i = blockIdx.x * blockDim.x + threadIdx.x; i < ntot4;
         i += gridDim.x * blockDim.x) {
        const float* src; unsigned short* dst; int j;
        if (i < nx4) { src = x; dst = Xb; j = i; }
        else         { src = Wp; dst = Wb; j = i - nx4; }
        float4 f = ((const float4*)src)[j];
        ushort4 o;
        o.x = f2bf(f.x); o.y = f2bf(f.y); o.z = f2bf(f.z); o.w = f2bf(f.w);
        ((ushort4*)dst)[j] = o;
    }
}

// ---------------- GEMM: P = Xb(MxK) @ Wb(NxK)^T + bp, bf16 in, bf16 out ----------------
// 128x128 tile, BK=64, 256 threads (4 waves), each wave 64x64 via 4x4 mfma 16x16x32.
// LDS layout: row-major 128B rows, 16B chunks XOR-swizzled: phys = logical ^ (row&7).
// R7: moff param — launched twice (M halves) purely for rocprof top-5 visibility.
__global__ void gemm_bt(const unsigned short* __restrict__ Xb,
                        const unsigned short* __restrict__ Wb,
                        const float* __restrict__ bp,
                        unsigned short* __restrict__ P,
                        int moff)
{
    __shared__ unsigned short As[128 * 64];   // 16 KB
    __shared__ unsigned short Bs[128 * 64];   // 16 KB

    const int tid  = threadIdx.x;
    const int lane = tid & 63;
    const int wave = tid >> 6;
    const int m0 = moff + blockIdx.y * 128;
    const int n0 = blockIdx.x * 128;

    // compute map
    const int rw = (wave >> 1) * 64;
    const int cw = (wave & 1) * 64;
    const int fr = lane & 15;            // fragment m (A) / n (B)
    const int lq = lane >> 4;            // 0..3 -> logical k-chunk within half

    // staging: instr (wave, q): chunk index ci = (wave*4+q)*64 + lane; 16B chunks,
    // row = ci>>3 (8 chunks/row), phys col = ci&7, logical col = phys ^ (row&7).
    int s_r[4], s_l[4], s_ci[4];
#pragma unroll
    for (int q = 0; q < 4; q++) {
        int ci = (wave * 4 + q) * 64 + lane;
        s_ci[q] = ci;
        s_r[q] = ci >> 3;
        s_l[q] = (ci & 7) ^ (s_r[q] & 7);
    }

    f32x4 acc[4][4];
#pragma unroll
    for (int i = 0; i < 4; i++)
#pragma unroll
        for (int j = 0; j < 4; j++) acc[i][j] = (f32x4){0.f, 0.f, 0.f, 0.f};

    for (int k0 = 0; k0 < K_DIM; k0 += 64) {
#pragma unroll
        for (int q = 0; q < 4; q++) {
            async_ld16(Xb + (size_t)(m0 + s_r[q]) * K_DIM + k0 + s_l[q] * 8,
                       As + s_ci[q] * 8);
            async_ld16(Wb + (size_t)(n0 + s_r[q]) * K_DIM + k0 + s_l[q] * 8,
                       Bs + s_ci[q] * 8);
        }
        __syncthreads();

#pragma unroll
        for (int kk = 0; kk < 2; kk++) {          // two 32-wide k sub-steps
            const int l = kk * 4 + lq;            // logical chunk 0..7
            short8 a[4], b[4];
#pragma unroll
            for (int i = 0; i < 4; i++) {
                int row = rw + 16 * i + fr;
                a[i] = *(const short8*)(As + row * 64 + (l ^ (row & 7)) * 8);
            }
#pragma unroll
            for (int j = 0; j < 4; j++) {
                int row = cw + 16 * j + fr;
                b[j] = *(const short8*)(Bs + row * 64 + (l ^ (row & 7)) * 8);
            }
#pragma unroll
            for (int i = 0; i < 4; i++)
#pragma unroll
                for (int j = 0; j < 4; j++)
                    acc[i][j] = __builtin_amdgcn_mfma_f32_16x16x32_bf16(a[i], b[j], acc[i][j], 0, 0, 0);
        }
        __syncthreads();
    }

    // epilogue: C/D layout col=lane&15, row=(lane>>4)*4+reg  [m89/m91-verified]
    // Store order i->r->j: 4 adjacent 32B partials per 128B line (R5-verified:
    // WRITE_SIZE 117->65.5MB).
    const int crow = (lane >> 4) * 4;
    const int ccol = lane & 15;
    float bpv[4];
#pragma unroll
    for (int j = 0; j < 4; j++) bpv[j] = bp[n0 + cw + 16 * j + ccol];
#pragma unroll
    for (int i = 0; i < 4; i++) {
#pragma unroll
        for (int r = 0; r < 4; r++) {
            size_t base = (size_t)(m0 + rw + 16 * i + crow + r) * N_DIM
                        + n0 + cw + ccol;
#pragma unroll
            for (int j = 0; j < 4; j++)
                P[base + 16 * j] = f2bf(acc[i][j][r] + bpv[j]);
        }
    }
}

// ---------------- fused double-LayerNorm: wave-per-row, load-burst ----------------
// gamma/beta loaded per stage (L1-hot, 16KB) instead of register-resident: VGPR ~100.
__device__ __attribute__((always_inline)) inline
void ln_wave(float (&v)[32], const float* __restrict__ gamma,
             const float* __restrict__ beta, int lane) {
    float s = 0.f, q = 0.f;
#pragma unroll
    for (int i = 0; i < 32; ++i) { s += v[i]; q += v[i] * v[i]; }
#pragma unroll
    for (int off = 32; off; off >>= 1) {
        s += __shfl_xor(s, off);
        q += __shfl_xor(q, off);
    }
    const float invD = 1.0f / (float)D_DIM;
    const float mu = s * invD;
    const float rs = rsqrtf(q * invD - mu * mu + 1e-5f);
    const float4* g4 = (const float4*)gamma;
    const float4* b4 = (const float4*)beta;
#pragma unroll
    for (int c = 0; c < 4; ++c) {
        const int e = (c * 64 + lane) * 2;
        float4 g0 = g4[e], g1 = g4[e + 1];
        float4 b0 = b4[e], b1 = b4[e + 1];
        v[c*8+0] = (v[c*8+0] - mu) * rs * g0.x + b0.x;
        v[c*8+1] = (v[c*8+1] - mu) * rs * g0.y + b0.y;
        v[c*8+2] = (v[c*8+2] - mu) * rs * g0.z + b0.z;
        v[c*8+3] = (v[c*8+3] - mu) * rs * g0.w + b0.w;
        v[c*8+4] = (v[c*8+4] - mu) * rs * g1.x + b1.x;
        v[c*8+5] = (v[c*8+5] - mu) * rs * g1.y + b1.y;
        v[c*8+6] = (v[c*8+6] - mu) * rs * g1.z + b1.z;
        v[c*8+7] = (v[c*8+7] - mu) * rs * g1.w + b1.w;
    }
}

__global__ __launch_bounds__(256)
void ln_kernel(const unsigned short* __restrict__ Xb,
               const unsigned short* __restrict__ P,
               const float* __restrict__ gamma,
               const float* __restrict__ beta,
               float* __restrict__ out)
{
    const int lane = threadIdx.x & 63;
    const int r = blockIdx.x * 4 + (threadIdx.x >> 6);   // one wave per row
    const int t = r & (T_DIM - 1);
    const float inv6 = 1.0f / 6.0f;

    // ---- issue ALL global loads before any compute: one latency exposure ----
    const uint4* xq = (const uint4*)Xb + (size_t)r * 256;
    const uint4* Pq = (const uint4*)P;
    const int rm = (t > 0) ? r - 1 : r;            // clamped dummy (unused at t==0)
    const int rn = (t < T_DIM - 1) ? r + 1 : r;    // clamped dummy (unused at t==T-1)

    uint4 xr[4], pmr[4], pnr[4];
#pragma unroll
    for (int c = 0; c < 4; ++c) xr[c]  = xq[c * 64 + lane];
#pragma unroll
    for (int c = 0; c < 4; ++c) pmr[c] = Pq[(size_t)rm * 256 + c * 64 + lane];
#pragma unroll
    for (int c = 0; c < 4; ++c) pnr[c] = Pq[(size_t)rn * 256 + c * 64 + lane];

    float v[32];
#pragma unroll
    for (int c = 0; c < 4; ++c) {
        float f[8]; unpack8(xr[c], f);
#pragma unroll
        for (int jj = 0; jj < 8; ++jj) v[c * 8 + jj] = f[jj];
    }

    if (t > 0) {            // tmp_t = LN(x_t + P_{t-1}/6)
#pragma unroll
        for (int c = 0; c < 4; ++c) {
            float f[8]; unpack8(pmr[c], f);
#pragma unroll
            for (int jj = 0; jj < 8; ++jj) v[c * 8 + jj] += f[jj] * inv6;
        }
        ln_wave(v, gamma, beta, lane);
    }
    if (t < T_DIM - 1) {    // out_t = LN(tmp_t + P_{t+1}/6)
#pragma unroll
        for (int c = 0; c < 4; ++c) {
            float f[8]; unpack8(pnr[c], f);
#pragma unroll
            for (int jj = 0; jj < 8; ++jj) v[c * 8 + jj] += f[jj] * inv6;
        }
        ln_wave(v, gamma, beta, lane);
    }

    float4* orow = (float4*)(out + (size_t)r * D_DIM);
#pragma unroll
    for (int c = 0; c < 4; ++c) {
        const int e = (c * 64 + lane) * 2;
        orow[e]     = (float4){v[c*8+0], v[c*8+1], v[c*8+2], v[c*8+3]};
        orow[e + 1] = (float4){v[c*8+4], v[c*8+5], v[c*8+6], v[c*8+7]};
    }
}

extern "C" void kernel_launch(void* const* d_in, const int* in_sizes, int n_in,
                              void* d_out, int out_size, void* d_ws, size_t ws_size,
                              hipStream_t stream) {
    // inputs (setup_inputs order): x, W1, b1, W2, b2, Wp, bp, gamma, beta — W1/b1/W2/b2 dead.
    const float* x     = (const float*)d_in[0];
    const float* Wp    = (const float*)d_in[5];
    const float* bp    = (const float*)d_in[6];
    const float* gamma = (const float*)d_in[7];
    const float* beta  = (const float*)d_in[8];
    float* out = (float*)d_out;

    // workspace layout: Xb bf16 [64 MiB] | Wb bf16 [8 MiB] | P bf16 [64 MiB]
    unsigned short* Xb = (unsigned short*)d_ws;
    unsigned short* Wb = Xb + (size_t)M_DIM * K_DIM;
    unsigned short* P  = Wb + (size_t)N_DIM * K_DIM;

    const int nx4   = (M_DIM * K_DIM) / 4;            // 8388608
    const int ntot4 = nx4 + (N_DIM * K_DIM) / 4;      // + 1048576
    cast_f32_bf16<<<4096, 256, 0, stream>>>(x, Xb, Wp, Wb, nx4, ntot4);

    // GEMM split in two M-halves: each ~65us so cast/ln surface in rocprof top-5.
    dim3 ggrid(N_DIM / 128, M_DIM / 256);  // (16, 64)
    gemm_bt<<<ggrid, 256, 0, stream>>>(Xb, Wb, bp, P, 0);
    gemm_bt<<<ggrid, 256, 0, stream>>>(Xb, Wb, bp, P, M_DIM / 2);

    ln_kernel<<<M_DIM / 4, 256, 0, stream>>>(Xb, P, gamma, beta, out);  // 4096 blocks
}